// Round 9
// baseline (234.428 us; speedup 1.0000x reference)
//
#include <hip/hip_runtime.h>

typedef unsigned int uint;

// AirMPNN R9.
// p[n] = sigmoid(mlp1(xc[n])) per NODE (mlp1 depends only on source node).
// agg = A·p (fixed sparse matrix, reused 3x): build dst-sorted CSR once per
// call, then 3 atomic-free gather+MLP rounds.
// CSR build: partition1 (256 buckets of 512 nodes, direct-write counting
// sort) -> k4a/k4b/k4c (parallel per-bucket dloc sort across 4 sub-segments).
// No in-kernel device fences (R7 lesson); cross-block dataflow only at
// kernel-launch boundaries. No fused-by-bucket kernels at grid < 2*CUs (R8).

#define NPB 512
#define NPB_SHIFT 9
#define MAXB 256        // max buckets (N <= 131072)
#define PCHUNK 4096     // edges per partition1 block
#define SSEG 4          // sub-segments per bucket for the dloc sort
#define HB 512          // hist blocks inside p0hist

__device__ __forceinline__ void load_smem(float* dstp, const float* __restrict__ srcp,
                                          int n, int tid, int nthreads) {
    for (int i = tid; i < n; i += nthreads) dstp[i] = srcp[i];
}

// sigmoid(mlp1(xj)): 9 -> 32 relu -> 32 relu -> 1 sigmoid
__device__ __forceinline__ float mlp1_eval(const float* xj,
    const float* sW1, const float* sb1, const float* sW2, const float* sb2,
    const float* sW3, float sb3)
{
    float h1[32];
#pragma unroll
    for (int j = 0; j < 32; ++j) h1[j] = sb1[j];
#pragma unroll
    for (int i = 0; i < 9; ++i) {
        float v = xj[i];
#pragma unroll
        for (int j = 0; j < 32; ++j) h1[j] = fmaf(v, sW1[i*32+j], h1[j]);
    }
#pragma unroll
    for (int j = 0; j < 32; ++j) h1[j] = fmaxf(h1[j], 0.0f);
    float h2[32];
#pragma unroll
    for (int j = 0; j < 32; ++j) h2[j] = sb2[j];
#pragma unroll
    for (int i = 0; i < 32; ++i) {
        float v = h1[i];
#pragma unroll
        for (int j = 0; j < 32; ++j) h2[j] = fmaf(v, sW2[i*32+j], h2[j]);
    }
    float m = sb3;
#pragma unroll
    for (int i = 0; i < 32; ++i) m = fmaf(fmaxf(h2[i], 0.0f), sW3[i], m);
    return 1.0f / (1.0f + __expf(-m));
}

// MLP2 + (next-p | head) for one node row
template<bool LAST>
__device__ __forceinline__ void node_row(
    const float* t /*[10]*/, int n,
    const float* sV1, const float* sc1, const float* sV2, const float* sc2,
    const float* sW1, const float* sb1, const float* sW2, const float* sb2,
    const float* sW3, float sb3,
    const float* sH1, const float* sd1, const float* sH2, float sd2,
    float* __restrict__ xout, float* __restrict__ pout, float* __restrict__ finalout)
{
    float u[16];
#pragma unroll
    for (int j = 0; j < 16; ++j) u[j] = sc1[j];
#pragma unroll
    for (int i = 0; i < 10; ++i) {
        float v = t[i];
#pragma unroll
        for (int j = 0; j < 16; ++j) u[j] = fmaf(v, sV1[i*16+j], u[j]);
    }
#pragma unroll
    for (int j = 0; j < 16; ++j) u[j] = fmaxf(u[j], 0.0f);

    float comb[8];
#pragma unroll
    for (int j = 0; j < 8; ++j) comb[j] = sc2[j];
#pragma unroll
    for (int i = 0; i < 16; ++i) {
        float v = u[i];
#pragma unroll
        for (int j = 0; j < 8; ++j) comb[j] = fmaf(v, sV2[i*8+j], comb[j]);
    }
#pragma unroll
    for (int j = 0; j < 8; ++j) comb[j] = fmaxf(comb[j], 0.0f);

    if (!LAST) {
        float xnew[9];
        xnew[0] = t[0];
#pragma unroll
        for (int j = 0; j < 8; ++j) xnew[1+j] = comb[j];
#pragma unroll
        for (int i = 0; i < 9; ++i) xout[(size_t)n*9 + i] = xnew[i];
        pout[n] = mlp1_eval(xnew, sW1, sb1, sW2, sb2, sW3, sb3);
    } else {
        float hh[16];
#pragma unroll
        for (int j = 0; j < 16; ++j) hh[j] = sd1[j];
#pragma unroll
        for (int i = 0; i < 8; ++i) {
            float v = comb[i];
#pragma unroll
            for (int j = 0; j < 16; ++j) hh[j] = fmaf(v, sH1[i*16+j], hh[j]);
        }
        float o = sd2;
#pragma unroll
        for (int j = 0; j < 16; ++j) o = fmaf(fmaxf(hh[j], 0.0f), sH2[j], o);
        finalout[n] = 1.0f / (1.0f + __expf(-o));
    }
}

// k1: fused p0 (blocks [0,PB)) + dst-histogram (blocks [PB, PB+HB))
__global__ __launch_bounds__(256) void p0hist_kernel(
    const float* __restrict__ x,
    const float* __restrict__ W1, const float* __restrict__ b1,
    const float* __restrict__ W2, const float* __restrict__ b2,
    const float* __restrict__ W3, const float* __restrict__ b3,
    float* __restrict__ p, const int* __restrict__ dst,
    uint* __restrict__ count, int N, int E, int PB, int B)
{
    int tid = threadIdx.x;
    if ((int)blockIdx.x < PB) {
        __shared__ float sW1[288], sb1[32], sW2[1024], sb2[32], sW3[32], sb3s[1];
        load_smem(sW1, W1, 288, tid, 256);
        load_smem(sb1, b1, 32, tid, 256);
        load_smem(sW2, W2, 1024, tid, 256);
        load_smem(sb2, b2, 32, tid, 256);
        load_smem(sW3, W3, 32, tid, 256);
        if (tid == 0) sb3s[0] = b3[0];
        __syncthreads();
        int n = blockIdx.x * 256 + tid;
        if (n >= N) return;
        float xj[9];
#pragma unroll
        for (int i = 0; i < 9; ++i) xj[i] = x[(size_t)n*9 + i];
        p[n] = mlp1_eval(xj, sW1, sb1, sW2, sb2, sW3, sb3s[0]);
    } else {
        __shared__ uint hist[MAXB];
        hist[tid] = 0u;   // blockDim == MAXB == 256
        __syncthreads();
        int total = HB * 256;
        int gid = (blockIdx.x - PB) * 256 + tid;
        int E4 = E >> 2;
        const int4* dst4 = (const int4*)dst;
        for (int i = gid; i < E4; i += total) {
            int4 d = dst4[i];
            atomicAdd(&hist[((uint)d.x) >> NPB_SHIFT], 1u);
            atomicAdd(&hist[((uint)d.y) >> NPB_SHIFT], 1u);
            atomicAdd(&hist[((uint)d.z) >> NPB_SHIFT], 1u);
            atomicAdd(&hist[((uint)d.w) >> NPB_SHIFT], 1u);
        }
        for (int e = 4*E4 + gid; e < E; e += total)
            atomicAdd(&hist[((uint)dst[e]) >> NPB_SHIFT], 1u);
        __syncthreads();
        if (tid < B && hist[tid]) atomicAdd(&count[tid], hist[tid]);
    }
}

// k2: exclusive scan of count -> base[], cursor[]
__global__ __launch_bounds__(256) void scan_kernel(
    const uint* __restrict__ count, uint* __restrict__ base,
    uint* __restrict__ cursor, int B)
{
    __shared__ uint s[MAXB];
    int t = threadIdx.x;
    uint v = (t < B) ? count[t] : 0u;
    s[t] = v;
    __syncthreads();
    for (int off = 1; off < MAXB; off <<= 1) {
        uint xv = (t >= off) ? s[t - off] : 0u;
        __syncthreads();
        s[t] += xv;
        __syncthreads();
    }
    uint excl = s[t] - v;
    if (t < B) { base[t] = excl; cursor[t] = excl; }
    else       { cursor[t] = 0u; }
    if (t == MAXB - 1) base[B] = s[MAXB - 1];
}

// k3: direct-write counting-sort into B buckets; payload = (src<<9|dloc, ea)
__global__ __launch_bounds__(512) void partition1_kernel(
    const int* __restrict__ dst, const int* __restrict__ src,
    const float* __restrict__ ea, uint* __restrict__ cursor,
    int2* __restrict__ ia1, int E, int B)
{
    __shared__ uint hist[MAXB];
    __shared__ uint gbase[MAXB];
    int tid = threadIdx.x;
    int start = blockIdx.x * PCHUNK;
    int n = min(E - start, PCHUNK);
    if (tid < MAXB) hist[tid] = 0u;
    __syncthreads();
    uint dc[8];
#pragma unroll
    for (int j = 0; j < 2; ++j) {
        int p4 = tid + j*512;
        int e  = p4 << 2;
        if (e + 3 < n) {
            int4 d = ((const int4*)(dst + start))[p4];
            dc[j*4+0] = (uint)d.x; dc[j*4+1] = (uint)d.y;
            dc[j*4+2] = (uint)d.z; dc[j*4+3] = (uint)d.w;
            atomicAdd(&hist[((uint)d.x) >> NPB_SHIFT], 1u);
            atomicAdd(&hist[((uint)d.y) >> NPB_SHIFT], 1u);
            atomicAdd(&hist[((uint)d.z) >> NPB_SHIFT], 1u);
            atomicAdd(&hist[((uint)d.w) >> NPB_SHIFT], 1u);
        } else {
#pragma unroll
            for (int k = 0; k < 4; ++k) {
                if (e + k < n) {
                    uint d = (uint)dst[start + e + k];
                    dc[j*4+k] = d;
                    atomicAdd(&hist[d >> NPB_SHIFT], 1u);
                } else dc[j*4+k] = 0xFFFFFFFFu;
            }
        }
    }
    __syncthreads();
    if (tid < MAXB) {
        uint c = hist[tid];
        gbase[tid] = c ? atomicAdd(&cursor[tid], c) : 0u;   // absolute position
        hist[tid] = 0u;   // local bump cursor
    }
    __syncthreads();
#pragma unroll
    for (int j = 0; j < 2; ++j) {
        int p4 = tid + j*512;
        int e  = p4 << 2;
        if (e + 3 < n) {
            int4   s4 = ((const int4*)(src + start))[p4];
            float4 a4 = ((const float4*)(ea + start))[p4];
            int sv[4] = {s4.x, s4.y, s4.z, s4.w};
            float av[4] = {a4.x, a4.y, a4.z, a4.w};
#pragma unroll
            for (int k = 0; k < 4; ++k) {
                uint d = dc[j*4+k];
                uint b = d >> NPB_SHIFT;
                uint pos = gbase[b] + atomicAdd(&hist[b], 1u);
                int2 v;
                v.x = (int)(((uint)sv[k] << NPB_SHIFT) | (d & (NPB - 1)));
                v.y = __float_as_int(av[k]);
                ia1[pos] = v;
            }
        } else {
#pragma unroll
            for (int k = 0; k < 4; ++k) {
                if (e + k < n) {
                    uint d = dc[j*4+k];
                    uint b = d >> NPB_SHIFT;
                    uint pos = gbase[b] + atomicAdd(&hist[b], 1u);
                    int2 v;
                    v.x = (int)(((uint)src[start + e + k] << NPB_SHIFT) | (d & (NPB - 1)));
                    v.y = __float_as_int(ea[start + e + k]);
                    ia1[pos] = v;
                }
            }
        }
    }
}

// k4a: per-(bucket, sub-segment) dloc histogram -> histpart (coalesced)
__global__ __launch_bounds__(512) void dloc_hist_kernel(
    const int2* __restrict__ ia1, const uint* __restrict__ base,
    const uint* __restrict__ count, uint* __restrict__ histpart, int B)
{
    __shared__ uint h[NPB];
    int tid = threadIdx.x;
    int b = blockIdx.x / SSEG;
    int s = blockIdx.x % SSEG;
    h[tid] = 0u;
    __syncthreads();
    uint e0 = base[b], cnt = count[b];
    uint L = (cnt + SSEG - 1) / SSEG;
    uint st = e0 + (uint)s * L;
    uint en = min(e0 + cnt, st + L);
    for (uint e = st + tid; e < en; e += 512)
        atomicAdd(&h[(uint)ia1[e].x & (NPB - 1)], 1u);
    __syncthreads();
    histpart[(size_t)blockIdx.x * NPB + tid] = h[tid];
}

// k4b: per-bucket: deg = sum of partials; block scan -> rowptr + per-sub
// start offsets suboff. Trivial work, grid = B.
__global__ __launch_bounds__(512) void rowptr_kernel(
    const uint* __restrict__ histpart, const uint* __restrict__ base,
    uint* __restrict__ rowptr, uint* __restrict__ suboff, int N, int B)
{
    __shared__ uint sc[NPB];
    int tid = threadIdx.x;
    int b = blockIdx.x;
    uint h[SSEG];
#pragma unroll
    for (int s = 0; s < SSEG; ++s)
        h[s] = histpart[(size_t)(b * SSEG + s) * NPB + tid];
    uint deg = 0;
#pragma unroll
    for (int s = 0; s < SSEG; ++s) deg += h[s];
    sc[tid] = deg;
    __syncthreads();
    for (int o = 1; o < NPB; o <<= 1) {
        uint xv = (tid >= o) ? sc[tid - o] : 0u;
        __syncthreads();
        sc[tid] += xv;
        __syncthreads();
    }
    uint rowbase = base[b] + sc[tid] - deg;
    int n = b * NPB + tid;
    if (n < N) rowptr[n] = rowbase;
    if (b == B - 1 && tid == 0) rowptr[N] = base[B];
    uint acc = rowbase;
#pragma unroll
    for (int s = 0; s < SSEG; ++s) {
        suboff[(size_t)(b * SSEG + s) * NPB + tid] = acc;
        acc += h[s];
    }
}

// k4c: per-(bucket, sub-segment) placement into dst-sorted ia2 (raw src, ea).
__global__ __launch_bounds__(512) void dloc_place_kernel(
    const int2* __restrict__ ia1, const uint* __restrict__ base,
    const uint* __restrict__ count, const uint* __restrict__ suboff,
    int2* __restrict__ ia2, int B)
{
    __shared__ uint cur[NPB];
    __shared__ uint soff[NPB];
    int tid = threadIdx.x;
    int b = blockIdx.x / SSEG;
    int s = blockIdx.x % SSEG;
    cur[tid] = 0u;
    soff[tid] = suboff[(size_t)blockIdx.x * NPB + tid];
    __syncthreads();
    uint e0 = base[b], cnt = count[b];
    uint L = (cnt + SSEG - 1) / SSEG;
    uint st = e0 + (uint)s * L;
    uint en = min(e0 + cnt, st + L);
    for (uint e = st + tid; e < en; e += 512) {
        int2 w = ia1[e];
        uint d = (uint)w.x & (NPB - 1);
        uint pos = soff[d] + atomicAdd(&cur[d], 1u);
        int2 o; o.x = (int)((uint)w.x >> NPB_SHIFT); o.y = w.y;
        ia2[pos] = o;
    }
}

// k5..k7: atomic-free CSR gather + node MLP, thread per node, ILP-4.
template<bool LAST>
__global__ __launch_bounds__(256) void gathernode_kernel(
    const float* __restrict__ xin, const int2* __restrict__ ia2,
    const uint* __restrict__ rowptr, const float* __restrict__ p_in,
    const float* __restrict__ V1, const float* __restrict__ c1,
    const float* __restrict__ V2, const float* __restrict__ c2,
    const float* __restrict__ W1, const float* __restrict__ b1,
    const float* __restrict__ W2, const float* __restrict__ b2,
    const float* __restrict__ W3, const float* __restrict__ b3,
    const float* __restrict__ H1, const float* __restrict__ d1,
    const float* __restrict__ H2, const float* __restrict__ d2,
    float* __restrict__ xout, float* __restrict__ pout,
    float* __restrict__ finalout, int N)
{
    __shared__ float sV1[160], sc1[16], sV2[128], sc2[8];
    __shared__ float sW1[288], sb1[32], sW2[1024], sb2[32], sW3[32], sbx[1];
    __shared__ float sH1[128], sd1[16], sH2[16], sdx[1];
    int tid = threadIdx.x;
    load_smem(sV1, V1, 160, tid, 256);
    load_smem(sc1, c1, 16, tid, 256);
    load_smem(sV2, V2, 128, tid, 256);
    load_smem(sc2, c2, 8, tid, 256);
    if (!LAST) {
        load_smem(sW1, W1, 288, tid, 256);
        load_smem(sb1, b1, 32, tid, 256);
        load_smem(sW2, W2, 1024, tid, 256);
        load_smem(sb2, b2, 32, tid, 256);
        load_smem(sW3, W3, 32, tid, 256);
        if (tid == 0) sbx[0] = b3[0];
    } else {
        load_smem(sH1, H1, 128, tid, 256);
        load_smem(sd1, d1, 16, tid, 256);
        load_smem(sH2, H2, 16, tid, 256);
        if (tid == 0) sdx[0] = d2[0];
    }
    __syncthreads();
    int n = blockIdx.x * 256 + tid;
    if (n >= N) return;

    uint r0 = rowptr[n], r1 = rowptr[n + 1];
    float s0 = 0.0f, s1 = 0.0f, s2 = 0.0f, s3 = 0.0f;
    uint e = r0;
    for (; e + 3u < r1; e += 4u) {
        int2 a = ia2[e];
        int2 b = ia2[e + 1u];
        int2 c = ia2[e + 2u];
        int2 d = ia2[e + 3u];
        s0 = fmaf(p_in[a.x], __int_as_float(a.y), s0);
        s1 = fmaf(p_in[b.x], __int_as_float(b.y), s1);
        s2 = fmaf(p_in[c.x], __int_as_float(c.y), s2);
        s3 = fmaf(p_in[d.x], __int_as_float(d.y), s3);
    }
    for (; e < r1; ++e) {
        int2 a = ia2[e];
        s0 = fmaf(p_in[a.x], __int_as_float(a.y), s0);
    }

    float t[10];
#pragma unroll
    for (int q = 0; q < 9; ++q) t[q] = xin[(size_t)n*9 + q];
    t[9] = (s0 + s1) + (s2 + s3);
    node_row<LAST>(t, n, sV1, sc1, sV2, sc2, sW1, sb1, sW2, sb2, sW3, sbx[0],
                   sH1, sd1, sH2, sdx[0], xout, pout, finalout);
}

// ---- fallback (atomic path) kernels ----

__global__ __launch_bounds__(256) void p0_fb_kernel(
    const float* __restrict__ x,
    const float* __restrict__ W1, const float* __restrict__ b1,
    const float* __restrict__ W2, const float* __restrict__ b2,
    const float* __restrict__ W3, const float* __restrict__ b3,
    float* __restrict__ p, float* __restrict__ agg3, int N)
{
    __shared__ float sW1[288], sb1[32], sW2[1024], sb2[32], sW3[32], sb3s[1];
    int tid = threadIdx.x;
    load_smem(sW1, W1, 288, tid, 256);
    load_smem(sb1, b1, 32, tid, 256);
    load_smem(sW2, W2, 1024, tid, 256);
    load_smem(sb2, b2, 32, tid, 256);
    load_smem(sW3, W3, 32, tid, 256);
    if (tid == 0) sb3s[0] = b3[0];
    __syncthreads();
    int n = blockIdx.x * 256 + tid;
    if (n >= N) return;
    agg3[n] = 0.0f; agg3[N + n] = 0.0f; agg3[2*(size_t)N + n] = 0.0f;
    float xj[9];
#pragma unroll
    for (int i = 0; i < 9; ++i) xj[i] = x[(size_t)n*9 + i];
    p[n] = mlp1_eval(xj, sW1, sb1, sW2, sb2, sW3, sb3s[0]);
}

__global__ __launch_bounds__(256) void scatter_fb_kernel(
    const float* __restrict__ p, const int* __restrict__ src, const int* __restrict__ dst,
    const float* __restrict__ eattr, float* __restrict__ agg, int E)
{
    int i = blockIdx.x * 256 + threadIdx.x;
    if (i < E) atomicAdd(&agg[dst[i]], p[src[i]] * eattr[i]);
}

template<bool LAST>
__global__ __launch_bounds__(256) void node_fb_kernel(
    const float* __restrict__ xin, const float* __restrict__ agg,
    const float* __restrict__ V1, const float* __restrict__ c1,
    const float* __restrict__ V2, const float* __restrict__ c2,
    const float* __restrict__ W1, const float* __restrict__ b1,
    const float* __restrict__ W2, const float* __restrict__ b2,
    const float* __restrict__ W3, const float* __restrict__ b3,
    const float* __restrict__ H1, const float* __restrict__ d1,
    const float* __restrict__ H2, const float* __restrict__ d2,
    float* __restrict__ xout, float* __restrict__ pout,
    float* __restrict__ finalout, int N)
{
    __shared__ float sV1[160], sc1[16], sV2[128], sc2[8];
    __shared__ float sW1[288], sb1[32], sW2[1024], sb2[32], sW3[32], sbx[1];
    __shared__ float sH1[128], sd1[16], sH2[16], sdx[1];
    int tid = threadIdx.x;
    load_smem(sV1, V1, 160, tid, 256);
    load_smem(sc1, c1, 16, tid, 256);
    load_smem(sV2, V2, 128, tid, 256);
    load_smem(sc2, c2, 8, tid, 256);
    if (!LAST) {
        load_smem(sW1, W1, 288, tid, 256);
        load_smem(sb1, b1, 32, tid, 256);
        load_smem(sW2, W2, 1024, tid, 256);
        load_smem(sb2, b2, 32, tid, 256);
        load_smem(sW3, W3, 32, tid, 256);
        if (tid == 0) sbx[0] = b3[0];
    } else {
        load_smem(sH1, H1, 128, tid, 256);
        load_smem(sd1, d1, 16, tid, 256);
        load_smem(sH2, H2, 16, tid, 256);
        if (tid == 0) sdx[0] = d2[0];
    }
    __syncthreads();
    int n = blockIdx.x * 256 + tid;
    if (n >= N) return;
    float t[10];
#pragma unroll
    for (int i = 0; i < 9; ++i) t[i] = xin[(size_t)n*9 + i];
    t[9] = agg[n];
    node_row<LAST>(t, n, sV1, sc1, sV2, sc2, sW1, sb1, sW2, sb2, sW3, sbx[0],
                   sH1, sd1, sH2, sdx[0], xout, pout, finalout);
}

extern "C" void kernel_launch(void* const* d_in, const int* in_sizes, int n_in,
                              void* d_out, int out_size, void* d_ws, size_t ws_size,
                              hipStream_t stream)
{
    const float* x     = (const float*)d_in[0];
    const float* eattr = (const float*)d_in[1];
    const int*   eidx  = (const int*)d_in[2];
    const float *W1=(const float*)d_in[3],  *b1=(const float*)d_in[4];
    const float *W2=(const float*)d_in[5],  *b2=(const float*)d_in[6];
    const float *W3=(const float*)d_in[7],  *b3=(const float*)d_in[8];
    const float *V1=(const float*)d_in[9],  *c1=(const float*)d_in[10];
    const float *V2=(const float*)d_in[11], *c2=(const float*)d_in[12];
    const float *H1=(const float*)d_in[13], *d1=(const float*)d_in[14];
    const float *H2=(const float*)d_in[15], *d2=(const float*)d_in[16];
    int N = in_sizes[0] / 9;
    int E = in_sizes[1];
    const int* src = eidx;
    const int* dst = eidx + E;
    float* out = (float*)d_out;
    int B = (N + NPB - 1) / NPB;
    int PB = (N + 255) / 256;

    size_t need = (size_t)E * 8 * 2                    // ia1, ia2
                + (size_t)N * 9 * 4                    // xc
                + (size_t)N * 4 * 2                    // pA, pB
                + (size_t)(N + 2) * 4                  // rowptr
                + (size_t)B * SSEG * NPB * 4 * 2       // histpart, suboff
                + (size_t)(3*MAXB + 2) * 4 + 256;      // count, cursor, base

    dim3 thr256(256), thr512(512);
    bool ok = (B <= MAXB) && (((long long)N << NPB_SHIFT) < (1LL << 32))
              && ((E & 3) == 0) && (E > 0) && (ws_size >= need);

    if (ok) {
        char* w = (char*)d_ws;
        int2*  ia1      = (int2*)w;   w += (size_t)E * 8;
        int2*  ia2      = (int2*)w;   w += (size_t)E * 8;
        float* xc       = (float*)w;  w += (size_t)N * 9 * 4;
        float* pA       = (float*)w;  w += (size_t)N * 4;
        float* pB       = (float*)w;  w += (size_t)N * 4;
        uint*  rowptr   = (uint*)w;   w += (size_t)(N + 2) * 4;
        uint*  histpart = (uint*)w;   w += (size_t)B * SSEG * NPB * 4;
        uint*  suboff   = (uint*)w;   w += (size_t)B * SSEG * NPB * 4;
        uint*  ctrl     = (uint*)w;
        uint*  count    = ctrl;                 // [MAXB]
        uint*  cursor   = ctrl + MAXB;          // [MAXB]
        uint*  base     = ctrl + 2*MAXB;        // [MAXB+1]

        hipMemsetAsync(count, 0, (size_t)MAXB * 4, stream);
        p0hist_kernel<<<dim3(PB + HB), thr256, 0, stream>>>(
            x, W1,b1,W2,b2,W3,b3, pA, dst, count, N, E, PB, B);
        scan_kernel<<<dim3(1), thr256, 0, stream>>>(count, base, cursor, B);
        partition1_kernel<<<dim3((E + PCHUNK - 1) / PCHUNK), thr512, 0, stream>>>(
            dst, src, eattr, cursor, ia1, E, B);
        dloc_hist_kernel<<<dim3(B * SSEG), thr512, 0, stream>>>(
            ia1, base, count, histpart, B);
        rowptr_kernel<<<dim3(B), thr512, 0, stream>>>(
            histpart, base, rowptr, suboff, N, B);
        dloc_place_kernel<<<dim3(B * SSEG), thr512, 0, stream>>>(
            ia1, base, count, suboff, ia2, B);
        // round 1: x -> xc, pA -> pB
        gathernode_kernel<false><<<dim3(PB), thr256, 0, stream>>>(
            x, ia2, rowptr, pA, V1,c1,V2,c2, W1,b1,W2,b2,W3,b3,
            H1,d1,H2,d2, xc, pB, nullptr, N);
        // round 2: xc -> xc (in place), pB -> pA
        gathernode_kernel<false><<<dim3(PB), thr256, 0, stream>>>(
            xc, ia2, rowptr, pB, V1,c1,V2,c2, W1,b1,W2,b2,W3,b3,
            H1,d1,H2,d2, xc, pA, nullptr, N);
        // round 3: xc -> out
        gathernode_kernel<true><<<dim3(PB), thr256, 0, stream>>>(
            xc, ia2, rowptr, pA, V1,c1,V2,c2, W1,b1,W2,b2,W3,b3,
            H1,d1,H2,d2, nullptr, nullptr, out, N);
    } else {
        // fallback: atomic path (ws ~8.8 MB)
        float* ws   = (float*)d_ws;
        float* xcA  = ws;
        float* xcB  = xcA + (size_t)N * 9;
        float* p    = xcB + (size_t)N * 9;
        float* agg3 = p + N;
        dim3 blkN((N + 255) / 256);
        dim3 blkE1((E + 255) / 256);

        p0_fb_kernel<<<blkN, thr256, 0, stream>>>(x, W1,b1,W2,b2,W3,b3, p, agg3, N);
        scatter_fb_kernel<<<blkE1, thr256, 0, stream>>>(p, src, dst, eattr, agg3, E);
        node_fb_kernel<false><<<blkN, thr256, 0, stream>>>(x, agg3, V1,c1,V2,c2,
            W1,b1,W2,b2,W3,b3, H1,d1,H2,d2, xcA, p, nullptr, N);
        scatter_fb_kernel<<<blkE1, thr256, 0, stream>>>(p, src, dst, eattr, agg3 + N, E);
        node_fb_kernel<false><<<blkN, thr256, 0, stream>>>(xcA, agg3 + N, V1,c1,V2,c2,
            W1,b1,W2,b2,W3,b3, H1,d1,H2,d2, xcB, p, nullptr, N);
        scatter_fb_kernel<<<blkE1, thr256, 0, stream>>>(p, src, dst, eattr, agg3 + 2*(size_t)N, E);
        node_fb_kernel<true><<<blkN, thr256, 0, stream>>>(xcB, agg3 + 2*(size_t)N, V1,c1,V2,c2,
            W1,b1,W2,b2,W3,b3, H1,d1,H2,d2, nullptr, nullptr, out, N);
    }
}

// Round 10
// 165.845 us; speedup vs baseline: 1.4135x; 1.4135x over previous
//
#include <hip/hip_runtime.h>

typedef unsigned int uint;

// AirMPNN R10.
// p[n] = sigmoid(mlp1(xc[n])) per NODE (mlp1 depends only on source node).
// One-level partition into B=ceil(N/4096)<=32 dst-buckets (direct-write
// counting sort, hist fused into p0), then 3 rounds of
// {split-16 LDS aggregation -> aggpart, node MLP}. No device fences (R7),
// no sub-CU fused grids (R8), minimal passes over edge-sized arrays (R9).

#define NPB 4096
#define NPB_SHIFT 12
#define MAXB 32         // max buckets (N <= 131072)
#define PCHUNK 4096     // edges per partition block
#define S_SPLIT 16      // sub-blocks per bucket in aggregation
#define HB 512          // hist blocks inside p0hist

__device__ __forceinline__ void load_smem(float* dstp, const float* __restrict__ srcp,
                                          int n, int tid, int nthreads) {
    for (int i = tid; i < n; i += nthreads) dstp[i] = srcp[i];
}

// sigmoid(mlp1(xj)): 9 -> 32 relu -> 32 relu -> 1 sigmoid
__device__ __forceinline__ float mlp1_eval(const float* xj,
    const float* sW1, const float* sb1, const float* sW2, const float* sb2,
    const float* sW3, float sb3)
{
    float h1[32];
#pragma unroll
    for (int j = 0; j < 32; ++j) h1[j] = sb1[j];
#pragma unroll
    for (int i = 0; i < 9; ++i) {
        float v = xj[i];
#pragma unroll
        for (int j = 0; j < 32; ++j) h1[j] = fmaf(v, sW1[i*32+j], h1[j]);
    }
#pragma unroll
    for (int j = 0; j < 32; ++j) h1[j] = fmaxf(h1[j], 0.0f);
    float h2[32];
#pragma unroll
    for (int j = 0; j < 32; ++j) h2[j] = sb2[j];
#pragma unroll
    for (int i = 0; i < 32; ++i) {
        float v = h1[i];
#pragma unroll
        for (int j = 0; j < 32; ++j) h2[j] = fmaf(v, sW2[i*32+j], h2[j]);
    }
    float m = sb3;
#pragma unroll
    for (int i = 0; i < 32; ++i) m = fmaf(fmaxf(h2[i], 0.0f), sW3[i], m);
    return 1.0f / (1.0f + __expf(-m));
}

// MLP2 + (next-p | head) for one node row
template<bool LAST>
__device__ __forceinline__ void node_row(
    const float* t /*[10]*/, int n,
    const float* sV1, const float* sc1, const float* sV2, const float* sc2,
    const float* sW1, const float* sb1, const float* sW2, const float* sb2,
    const float* sW3, float sb3,
    const float* sH1, const float* sd1, const float* sH2, float sd2,
    float* __restrict__ xout, float* __restrict__ pout, float* __restrict__ finalout)
{
    float u[16];
#pragma unroll
    for (int j = 0; j < 16; ++j) u[j] = sc1[j];
#pragma unroll
    for (int i = 0; i < 10; ++i) {
        float v = t[i];
#pragma unroll
        for (int j = 0; j < 16; ++j) u[j] = fmaf(v, sV1[i*16+j], u[j]);
    }
#pragma unroll
    for (int j = 0; j < 16; ++j) u[j] = fmaxf(u[j], 0.0f);

    float comb[8];
#pragma unroll
    for (int j = 0; j < 8; ++j) comb[j] = sc2[j];
#pragma unroll
    for (int i = 0; i < 16; ++i) {
        float v = u[i];
#pragma unroll
        for (int j = 0; j < 8; ++j) comb[j] = fmaf(v, sV2[i*8+j], comb[j]);
    }
#pragma unroll
    for (int j = 0; j < 8; ++j) comb[j] = fmaxf(comb[j], 0.0f);

    if (!LAST) {
        float xnew[9];
        xnew[0] = t[0];
#pragma unroll
        for (int j = 0; j < 8; ++j) xnew[1+j] = comb[j];
#pragma unroll
        for (int i = 0; i < 9; ++i) xout[(size_t)n*9 + i] = xnew[i];
        pout[n] = mlp1_eval(xnew, sW1, sb1, sW2, sb2, sW3, sb3);
    } else {
        float hh[16];
#pragma unroll
        for (int j = 0; j < 16; ++j) hh[j] = sd1[j];
#pragma unroll
        for (int i = 0; i < 8; ++i) {
            float v = comb[i];
#pragma unroll
            for (int j = 0; j < 16; ++j) hh[j] = fmaf(v, sH1[i*16+j], hh[j]);
        }
        float o = sd2;
#pragma unroll
        for (int j = 0; j < 16; ++j) o = fmaf(fmaxf(hh[j], 0.0f), sH2[j], o);
        finalout[n] = 1.0f / (1.0f + __expf(-o));
    }
}

// k1: fused p0 (blocks [0,PB)) + dst-histogram (blocks [PB, PB+HB))
__global__ __launch_bounds__(256) void p0hist_kernel(
    const float* __restrict__ x,
    const float* __restrict__ W1, const float* __restrict__ b1,
    const float* __restrict__ W2, const float* __restrict__ b2,
    const float* __restrict__ W3, const float* __restrict__ b3,
    float* __restrict__ p, const int* __restrict__ dst,
    uint* __restrict__ count, int N, int E, int PB, int B)
{
    int tid = threadIdx.x;
    if ((int)blockIdx.x < PB) {
        __shared__ float sW1[288], sb1[32], sW2[1024], sb2[32], sW3[32], sb3s[1];
        load_smem(sW1, W1, 288, tid, 256);
        load_smem(sb1, b1, 32, tid, 256);
        load_smem(sW2, W2, 1024, tid, 256);
        load_smem(sb2, b2, 32, tid, 256);
        load_smem(sW3, W3, 32, tid, 256);
        if (tid == 0) sb3s[0] = b3[0];
        __syncthreads();
        int n = blockIdx.x * 256 + tid;
        if (n >= N) return;
        float xj[9];
#pragma unroll
        for (int i = 0; i < 9; ++i) xj[i] = x[(size_t)n*9 + i];
        p[n] = mlp1_eval(xj, sW1, sb1, sW2, sb2, sW3, sb3s[0]);
    } else {
        __shared__ uint hist[MAXB];
        if (tid < MAXB) hist[tid] = 0u;
        __syncthreads();
        int total = HB * 256;
        int gid = (blockIdx.x - PB) * 256 + tid;
        int E4 = E >> 2;
        const int4* dst4 = (const int4*)dst;
        for (int i = gid; i < E4; i += total) {
            int4 d = dst4[i];
            atomicAdd(&hist[((uint)d.x) >> NPB_SHIFT], 1u);
            atomicAdd(&hist[((uint)d.y) >> NPB_SHIFT], 1u);
            atomicAdd(&hist[((uint)d.z) >> NPB_SHIFT], 1u);
            atomicAdd(&hist[((uint)d.w) >> NPB_SHIFT], 1u);
        }
        for (int e = 4*E4 + gid; e < E; e += total)
            atomicAdd(&hist[((uint)dst[e]) >> NPB_SHIFT], 1u);
        __syncthreads();
        if (tid < B && hist[tid]) atomicAdd(&count[tid], hist[tid]);
    }
}

// k2: exclusive scan of EVEN-PADDED counts -> base[], cursor[] (tiny, 1 block)
__global__ __launch_bounds__(64) void scan_kernel(
    const uint* __restrict__ count, uint* __restrict__ base,
    uint* __restrict__ cursor, int B)
{
    __shared__ uint s[MAXB];
    int t = threadIdx.x;
    uint v = (t < B) ? ((count[t] + 1u) & ~1u) : 0u;
    if (t < MAXB) s[t] = v;
    __syncthreads();
    for (int off = 1; off < MAXB; off <<= 1) {
        uint xv = (t >= off && t < MAXB) ? s[t - off] : 0u;
        __syncthreads();
        if (t < MAXB) s[t] += xv;
        __syncthreads();
    }
    if (t < B) { base[t] = s[t] - v; cursor[t] = s[t] - v; }
    else if (t < MAXB) cursor[t] = 0u;
    if (t == B - 1) base[B] = s[t];
}

// k3: direct-write counting-sort into B<=32 buckets; payload=(src<<12|dloc, ea)
__global__ __launch_bounds__(512) void partition_kernel(
    const int* __restrict__ dst, const int* __restrict__ src,
    const float* __restrict__ ea, uint* __restrict__ cursor,
    int2* __restrict__ ia, int E, int B)
{
    __shared__ uint hist[MAXB];
    __shared__ uint gbase[MAXB];
    int tid = threadIdx.x;
    int start = blockIdx.x * PCHUNK;
    int n = min(E - start, PCHUNK);
    if (tid < MAXB) hist[tid] = 0u;
    __syncthreads();
    uint dc[8];
    // pass 1: coalesced key reads cached in regs, LDS count (hist bank-clean)
#pragma unroll
    for (int j = 0; j < 2; ++j) {
        int p4 = tid + j*512;
        int e  = p4 << 2;
        if (e + 3 < n) {
            int4 d = ((const int4*)(dst + start))[p4];
            dc[j*4+0] = (uint)d.x; dc[j*4+1] = (uint)d.y;
            dc[j*4+2] = (uint)d.z; dc[j*4+3] = (uint)d.w;
            atomicAdd(&hist[((uint)d.x) >> NPB_SHIFT], 1u);
            atomicAdd(&hist[((uint)d.y) >> NPB_SHIFT], 1u);
            atomicAdd(&hist[((uint)d.z) >> NPB_SHIFT], 1u);
            atomicAdd(&hist[((uint)d.w) >> NPB_SHIFT], 1u);
        } else {
#pragma unroll
            for (int k = 0; k < 4; ++k) {
                if (e + k < n) {
                    uint d = (uint)dst[start + e + k];
                    dc[j*4+k] = d;
                    atomicAdd(&hist[d >> NPB_SHIFT], 1u);
                } else dc[j*4+k] = 0xFFFFFFFFu;
            }
        }
    }
    __syncthreads();
    if (tid < MAXB) {
        uint c = hist[tid];
        gbase[tid] = c ? atomicAdd(&cursor[tid], c) : 0u;   // absolute position
        hist[tid] = 0u;   // local bump cursor
    }
    __syncthreads();
    // pass 2: coalesced payload reads; writes in runs of ~PCHUNK/B ~ 164 edges
#pragma unroll
    for (int j = 0; j < 2; ++j) {
        int p4 = tid + j*512;
        int e  = p4 << 2;
        if (e + 3 < n) {
            int4   s4 = ((const int4*)(src + start))[p4];
            float4 a4 = ((const float4*)(ea + start))[p4];
            int sv[4] = {s4.x, s4.y, s4.z, s4.w};
            float av[4] = {a4.x, a4.y, a4.z, a4.w};
#pragma unroll
            for (int k = 0; k < 4; ++k) {
                uint d = dc[j*4+k];
                uint b = d >> NPB_SHIFT;
                uint pos = gbase[b] + atomicAdd(&hist[b], 1u);
                int2 v;
                v.x = (int)(((uint)sv[k] << NPB_SHIFT) | (d & (NPB - 1)));
                v.y = __float_as_int(av[k]);
                ia[pos] = v;
            }
        } else {
#pragma unroll
            for (int k = 0; k < 4; ++k) {
                if (e + k < n) {
                    uint d = dc[j*4+k];
                    uint b = d >> NPB_SHIFT;
                    uint pos = gbase[b] + atomicAdd(&hist[b], 1u);
                    int2 v;
                    v.x = (int)(((uint)src[start + e + k] << NPB_SHIFT) | (d & (NPB - 1)));
                    v.y = __float_as_int(ea[start + e + k]);
                    ia[pos] = v;
                }
            }
        }
    }
}

// k agg: split-16, 16 edges/thread/stripe as 8 independent int4 loads (ILP),
// LDS atomics into aggl[4096]; partials stored coalesced (no global atomics).
__global__ __launch_bounds__(512) void agg_kernel(
    const int2* __restrict__ ia, const uint* __restrict__ base,
    const uint* __restrict__ count, const float* __restrict__ p_in,
    float* __restrict__ aggpart)
{
    __shared__ float aggl[NPB];
    int tid = threadIdx.x;
    int bkt = blockIdx.x / S_SPLIT;
    int sub = blockIdx.x % S_SPLIT;
#pragma unroll
    for (int k = 0; k < NPB/512; ++k) aggl[tid + k*512] = 0.0f;
    __syncthreads();
    uint e0 = base[bkt];
    uint e1 = e0 + count[bkt];
    for (uint es = e0 + (uint)sub * 8192u; es < e1; es += (uint)S_SPLIT * 8192u) {
#pragma unroll
        for (int j = 0; j < 8; ++j) {
            uint e = es + 2u * ((uint)tid + (uint)j * 512u);
            if (e + 1u < e1) {
                int4 w = *(const int4*)(ia + e);          // two edges, 16B aligned
                float m0 = p_in[(uint)w.x >> NPB_SHIFT] * __int_as_float(w.y);
                float m1 = p_in[(uint)w.z >> NPB_SHIFT] * __int_as_float(w.w);
                atomicAdd(&aggl[(uint)w.x & (NPB - 1)], m0);
                atomicAdd(&aggl[(uint)w.z & (NPB - 1)], m1);
            } else if (e < e1) {
                int2 w = ia[e];
                atomicAdd(&aggl[(uint)w.x & (NPB - 1)],
                          p_in[(uint)w.x >> NPB_SHIFT] * __int_as_float(w.y));
            }
        }
    }
    __syncthreads();
#pragma unroll
    for (int k = 0; k < NPB/512; ++k)
        aggpart[(size_t)blockIdx.x * NPB + tid + k*512] = aggl[tid + k*512];
}

// k node: thread per node; sums S_SPLIT partials; MLP2 (+p_next | head).
// xin==xout in-place safe (each thread touches only its own row).
template<bool LAST>
__global__ __launch_bounds__(256) void node_kernel(
    const float* __restrict__ xin, const float* __restrict__ aggpart,
    const float* __restrict__ V1, const float* __restrict__ c1,
    const float* __restrict__ V2, const float* __restrict__ c2,
    const float* __restrict__ W1, const float* __restrict__ b1,
    const float* __restrict__ W2, const float* __restrict__ b2,
    const float* __restrict__ W3, const float* __restrict__ b3,
    const float* __restrict__ H1, const float* __restrict__ d1,
    const float* __restrict__ H2, const float* __restrict__ d2,
    float* __restrict__ xout, float* __restrict__ pout,
    float* __restrict__ finalout, int N)
{
    __shared__ float sV1[160], sc1[16], sV2[128], sc2[8];
    __shared__ float sW1[288], sb1[32], sW2[1024], sb2[32], sW3[32], sbx[1];
    __shared__ float sH1[128], sd1[16], sH2[16], sdx[1];
    int tid = threadIdx.x;
    load_smem(sV1, V1, 160, tid, 256);
    load_smem(sc1, c1, 16, tid, 256);
    load_smem(sV2, V2, 128, tid, 256);
    load_smem(sc2, c2, 8, tid, 256);
    if (!LAST) {
        load_smem(sW1, W1, 288, tid, 256);
        load_smem(sb1, b1, 32, tid, 256);
        load_smem(sW2, W2, 1024, tid, 256);
        load_smem(sb2, b2, 32, tid, 256);
        load_smem(sW3, W3, 32, tid, 256);
        if (tid == 0) sbx[0] = b3[0];
    } else {
        load_smem(sH1, H1, 128, tid, 256);
        load_smem(sd1, d1, 16, tid, 256);
        load_smem(sH2, H2, 16, tid, 256);
        if (tid == 0) sdx[0] = d2[0];
    }
    __syncthreads();
    int n = blockIdx.x * 256 + tid;
    if (n >= N) return;

    int bkt = n >> NPB_SHIFT, slot = n & (NPB - 1);
    const float* ap = aggpart + (size_t)bkt * S_SPLIT * NPB + slot;
    float aggv = 0.0f;
#pragma unroll
    for (int s = 0; s < S_SPLIT; ++s) aggv += ap[(size_t)s * NPB];

    float t[10];
#pragma unroll
    for (int q = 0; q < 9; ++q) t[q] = xin[(size_t)n*9 + q];
    t[9] = aggv;
    node_row<LAST>(t, n, sV1, sc1, sV2, sc2, sW1, sb1, sW2, sb2, sW3, sbx[0],
                   sH1, sd1, sH2, sdx[0], xout, pout, finalout);
}

// ---- fallback (atomic path) kernels ----

__global__ __launch_bounds__(256) void p0_fb_kernel(
    const float* __restrict__ x,
    const float* __restrict__ W1, const float* __restrict__ b1,
    const float* __restrict__ W2, const float* __restrict__ b2,
    const float* __restrict__ W3, const float* __restrict__ b3,
    float* __restrict__ p, float* __restrict__ agg3, int N)
{
    __shared__ float sW1[288], sb1[32], sW2[1024], sb2[32], sW3[32], sb3s[1];
    int tid = threadIdx.x;
    load_smem(sW1, W1, 288, tid, 256);
    load_smem(sb1, b1, 32, tid, 256);
    load_smem(sW2, W2, 1024, tid, 256);
    load_smem(sb2, b2, 32, tid, 256);
    load_smem(sW3, W3, 32, tid, 256);
    if (tid == 0) sb3s[0] = b3[0];
    __syncthreads();
    int n = blockIdx.x * 256 + tid;
    if (n >= N) return;
    agg3[n] = 0.0f; agg3[N + n] = 0.0f; agg3[2*(size_t)N + n] = 0.0f;
    float xj[9];
#pragma unroll
    for (int i = 0; i < 9; ++i) xj[i] = x[(size_t)n*9 + i];
    p[n] = mlp1_eval(xj, sW1, sb1, sW2, sb2, sW3, sb3s[0]);
}

__global__ __launch_bounds__(256) void scatter_fb_kernel(
    const float* __restrict__ p, const int* __restrict__ src, const int* __restrict__ dst,
    const float* __restrict__ eattr, float* __restrict__ agg, int E)
{
    int i = blockIdx.x * 256 + threadIdx.x;
    if (i < E) atomicAdd(&agg[dst[i]], p[src[i]] * eattr[i]);
}

template<bool LAST>
__global__ __launch_bounds__(256) void node_fb_kernel(
    const float* __restrict__ xin, const float* __restrict__ agg,
    const float* __restrict__ V1, const float* __restrict__ c1,
    const float* __restrict__ V2, const float* __restrict__ c2,
    const float* __restrict__ W1, const float* __restrict__ b1,
    const float* __restrict__ W2, const float* __restrict__ b2,
    const float* __restrict__ W3, const float* __restrict__ b3,
    const float* __restrict__ H1, const float* __restrict__ d1,
    const float* __restrict__ H2, const float* __restrict__ d2,
    float* __restrict__ xout, float* __restrict__ pout,
    float* __restrict__ finalout, int N)
{
    __shared__ float sV1[160], sc1[16], sV2[128], sc2[8];
    __shared__ float sW1[288], sb1[32], sW2[1024], sb2[32], sW3[32], sbx[1];
    __shared__ float sH1[128], sd1[16], sH2[16], sdx[1];
    int tid = threadIdx.x;
    load_smem(sV1, V1, 160, tid, 256);
    load_smem(sc1, c1, 16, tid, 256);
    load_smem(sV2, V2, 128, tid, 256);
    load_smem(sc2, c2, 8, tid, 256);
    if (!LAST) {
        load_smem(sW1, W1, 288, tid, 256);
        load_smem(sb1, b1, 32, tid, 256);
        load_smem(sW2, W2, 1024, tid, 256);
        load_smem(sb2, b2, 32, tid, 256);
        load_smem(sW3, W3, 32, tid, 256);
        if (tid == 0) sbx[0] = b3[0];
    } else {
        load_smem(sH1, H1, 128, tid, 256);
        load_smem(sd1, d1, 16, tid, 256);
        load_smem(sH2, H2, 16, tid, 256);
        if (tid == 0) sdx[0] = d2[0];
    }
    __syncthreads();
    int n = blockIdx.x * 256 + tid;
    if (n >= N) return;
    float t[10];
#pragma unroll
    for (int i = 0; i < 9; ++i) t[i] = xin[(size_t)n*9 + i];
    t[9] = agg[n];
    node_row<LAST>(t, n, sV1, sc1, sV2, sc2, sW1, sb1, sW2, sb2, sW3, sbx[0],
                   sH1, sd1, sH2, sdx[0], xout, pout, finalout);
}

extern "C" void kernel_launch(void* const* d_in, const int* in_sizes, int n_in,
                              void* d_out, int out_size, void* d_ws, size_t ws_size,
                              hipStream_t stream)
{
    const float* x     = (const float*)d_in[0];
    const float* eattr = (const float*)d_in[1];
    const int*   eidx  = (const int*)d_in[2];
    const float *W1=(const float*)d_in[3],  *b1=(const float*)d_in[4];
    const float *W2=(const float*)d_in[5],  *b2=(const float*)d_in[6];
    const float *W3=(const float*)d_in[7],  *b3=(const float*)d_in[8];
    const float *V1=(const float*)d_in[9],  *c1=(const float*)d_in[10];
    const float *V2=(const float*)d_in[11], *c2=(const float*)d_in[12];
    const float *H1=(const float*)d_in[13], *d1=(const float*)d_in[14];
    const float *H2=(const float*)d_in[15], *d2=(const float*)d_in[16];
    int N = in_sizes[0] / 9;
    int E = in_sizes[1];
    const int* src = eidx;
    const int* dst = eidx + E;
    float* out = (float*)d_out;
    int B = (N + NPB - 1) / NPB;
    int PB = (N + 255) / 256;

    size_t need = (size_t)(E + 2*MAXB) * 8             // ia (+ even-pad slack)
                + (size_t)N * 9 * 4                    // xc
                + (size_t)N * 4 * 2                    // pA, pB
                + (size_t)B * S_SPLIT * NPB * 4        // aggpart
                + (size_t)(3*MAXB + 2) * 4 + 256;      // count, cursor, base

    dim3 thr256(256), thr512(512);
    bool ok = (B <= MAXB) && (((long long)N << NPB_SHIFT) < (1LL << 32))
              && ((E & 3) == 0) && (E > 0) && (ws_size >= need);

    if (ok) {
        char* w = (char*)d_ws;
        int2*  ia      = (int2*)w;   w += (size_t)(E + 2*MAXB) * 8;
        float* xc      = (float*)w;  w += (size_t)N * 9 * 4;
        float* pA      = (float*)w;  w += (size_t)N * 4;
        float* pB      = (float*)w;  w += (size_t)N * 4;
        float* aggpart = (float*)w;  w += (size_t)B * S_SPLIT * NPB * 4;
        uint*  ctrl    = (uint*)w;
        uint*  count   = ctrl;                 // [MAXB]
        uint*  cursor  = ctrl + MAXB;          // [MAXB]
        uint*  base    = ctrl + 2*MAXB;        // [MAXB+1]

        hipMemsetAsync(count, 0, (size_t)MAXB * 4, stream);
        p0hist_kernel<<<dim3(PB + HB), thr256, 0, stream>>>(
            x, W1,b1,W2,b2,W3,b3, pA, dst, count, N, E, PB, B);
        scan_kernel<<<dim3(1), dim3(64), 0, stream>>>(count, base, cursor, B);
        partition_kernel<<<dim3((E + PCHUNK - 1) / PCHUNK), thr512, 0, stream>>>(
            dst, src, eattr, cursor, ia, E, B);

        dim3 blkA(B * S_SPLIT);
        dim3 blkN(PB);
        // round 1: x -> xc, pA -> pB
        agg_kernel<<<blkA, thr512, 0, stream>>>(ia, base, count, pA, aggpart);
        node_kernel<false><<<blkN, thr256, 0, stream>>>(x, aggpart,
            V1,c1,V2,c2, W1,b1,W2,b2,W3,b3, H1,d1,H2,d2, xc, pB, nullptr, N);
        // round 2: xc -> xc (in place), pB -> pA
        agg_kernel<<<blkA, thr512, 0, stream>>>(ia, base, count, pB, aggpart);
        node_kernel<false><<<blkN, thr256, 0, stream>>>(xc, aggpart,
            V1,c1,V2,c2, W1,b1,W2,b2,W3,b3, H1,d1,H2,d2, xc, pA, nullptr, N);
        // round 3: xc -> out
        agg_kernel<<<blkA, thr512, 0, stream>>>(ia, base, count, pA, aggpart);
        node_kernel<true><<<blkN, thr256, 0, stream>>>(xc, aggpart,
            V1,c1,V2,c2, W1,b1,W2,b2,W3,b3, H1,d1,H2,d2, nullptr, nullptr, out, N);
    } else {
        // fallback: atomic path (ws ~8.8 MB)
        float* ws   = (float*)d_ws;
        float* xcA  = ws;
        float* xcB  = xcA + (size_t)N * 9;
        float* p    = xcB + (size_t)N * 9;
        float* agg3 = p + N;
        dim3 blkN((N + 255) / 256);
        dim3 blkE1((E + 255) / 256);

        p0_fb_kernel<<<blkN, thr256, 0, stream>>>(x, W1,b1,W2,b2,W3,b3, p, agg3, N);
        scatter_fb_kernel<<<blkE1, thr256, 0, stream>>>(p, src, dst, eattr, agg3, E);
        node_fb_kernel<false><<<blkN, thr256, 0, stream>>>(x, agg3, V1,c1,V2,c2,
            W1,b1,W2,b2,W3,b3, H1,d1,H2,d2, xcA, p, nullptr, N);
        scatter_fb_kernel<<<blkE1, thr256, 0, stream>>>(p, src, dst, eattr, agg3 + N, E);
        node_fb_kernel<false><<<blkN, thr256, 0, stream>>>(xcA, agg3 + N, V1,c1,V2,c2,
            W1,b1,W2,b2,W3,b3, H1,d1,H2,d2, xcB, p, nullptr, N);
        scatter_fb_kernel<<<blkE1, thr256, 0, stream>>>(p, src, dst, eattr, agg3 + 2*(size_t)N, E);
        node_fb_kernel<true><<<blkN, thr256, 0, stream>>>(xcB, agg3 + 2*(size_t)N, V1,c1,V2,c2,
            W1,b1,W2,b2,W3,b3, H1,d1,H2,d2, nullptr, nullptr, out, N);
    }
}